// Round 20
// baseline (773.505 us; speedup 1.0000x reference)
//
#include <hip/hip_runtime.h>
#include <hip/hip_bf16.h>

#define NTOK 8192
#define DIM 1024
#define NEXP 8
#define NT 256   // virtual K tiles: 16 segments (expert x half) x 16 tiles of BK=64
#define BK 64
#define NELEMZ ((size_t)NTOK * DIM)

typedef float f32x4 __attribute__((ext_vector_type(4)));
typedef float f32x16 __attribute__((ext_vector_type(16)));
typedef short s16x8 __attribute__((ext_vector_type(8)));
typedef unsigned short u16;
typedef unsigned short u16x4 __attribute__((ext_vector_type(4)));

__device__ __forceinline__ u16 f2bf(float f) {
    __hip_bfloat16 h = __float2bfloat16(f);
    return *reinterpret_cast<u16*>(&h);
}
__device__ __forceinline__ float bf2f(u16 u) {
    unsigned v = ((unsigned)u) << 16;
    return __uint_as_float(v);
}

#define GLOAD16(gsrc, ldst)                                                     \
    __builtin_amdgcn_global_load_lds(                                           \
        (const __attribute__((address_space(1))) void*)(gsrc),                  \
        (__attribute__((address_space(3))) void*)(ldst), 16, 0, 0)

#define MFMA32(a, b, c) __builtin_amdgcn_mfma_f32_32x32x16_bf16((a), (b), (c), 0, 0, 0)
#define SGB() __builtin_amdgcn_sched_barrier(0)

// ---------------- gates: softmax(z_flat @ Wg^T + bg) -> gates[n][e] ----------
__global__ __launch_bounds__(256) void gates_kernel(
    const float* __restrict__ zr, const float* __restrict__ zi,
    const float* __restrict__ Wg, const float* __restrict__ bg,
    float* __restrict__ gates)
{
    const int wave = threadIdx.x >> 6, lane = threadIdx.x & 63;
    const int n = blockIdx.x * 4 + wave;

    float v[32];
    const float* zrp = zr + (size_t)n * DIM;
    const float* zip = zi + (size_t)n * DIM;
#pragma unroll
    for (int j = 0; j < 16; ++j) v[j] = zrp[j * 64 + lane];
#pragma unroll
    for (int j = 0; j < 16; ++j) v[16 + j] = zip[j * 64 + lane];

    float s[NEXP];
#pragma unroll
    for (int e = 0; e < NEXP; ++e) {
        const float* wrow = Wg + (size_t)e * (2 * DIM);
        float a = 0.f;
#pragma unroll
        for (int j = 0; j < 32; ++j) a += v[j] * wrow[j * 64 + lane];
#pragma unroll
        for (int m = 32; m; m >>= 1) a += __shfl_xor(a, m);
        s[e] = a + bg[e];
    }
    float mx = s[0];
#pragma unroll
    for (int e = 1; e < NEXP; ++e) mx = fmaxf(mx, s[e]);
    float p[NEXP], sum = 0.f;
#pragma unroll
    for (int e = 0; e < NEXP; ++e) { p[e] = expf(s[e] - mx); sum += p[e]; }
    const float inv = 1.f / sum;
    if (lane == 0) {
#pragma unroll
        for (int e = 0; e < NEXP; ++e) gates[(size_t)n * NEXP + e] = p[e] * inv;
    }
}

// ---------------- fp32 -> bf16 conversion (z and W) ----------------
__global__ __launch_bounds__(256) void cvt4_kernel(
    const float* __restrict__ zr, const float* __restrict__ zi,
    const float* __restrict__ Wr, const float* __restrict__ Wi,
    u16* __restrict__ zr16, u16* __restrict__ zi16,
    u16* __restrict__ Wr16, u16* __restrict__ Wi16)
{
    const size_t total = NELEMZ / 4;
    for (size_t i = (size_t)blockIdx.x * 256 + threadIdx.x; i < total;
         i += (size_t)gridDim.x * 256) {
        f32x4 a = ((const f32x4*)zr)[i];
        f32x4 b = ((const f32x4*)zi)[i];
        f32x4 c = ((const f32x4*)Wr)[i];
        f32x4 d = ((const f32x4*)Wi)[i];
        u16x4 pa, pb, pc, pd;
#pragma unroll
        for (int j = 0; j < 4; ++j) {
            pa[j] = f2bf(a[j]); pb[j] = f2bf(b[j]);
            pc[j] = f2bf(c[j]); pd[j] = f2bf(d[j]);
        }
        ((u16x4*)zr16)[i] = pa;
        ((u16x4*)zi16)[i] = pb;
        ((u16x4*)Wr16)[i] = pc;
        ((u16x4*)Wi16)[i] = pd;
    }
}

// ---------------- main MoE GEMM: 32x32x16 MFMA + FRAGMENT-ORDER LDS ----------
// 512 threads = 8 waves (2M x 4N), per-wave 128x64 via 4x2 tiles of 32x32:
// acc = f32x16[4][2]. BK=64 -> 4 k-steps of K=16.
// LDS stores tiles in MFMA-FRAGMENT ORDER: chunk c = ((rb*4+ks)*64 + lane),
// where rb=row>>5 (32-row block), lane's elems = row rb*32+(lane&31),
// k=(lane>>5)*8+ks*16. Fragment read = 64 lanes x consecutive 16B chunks
// = 1024B linear -> ZERO bank conflicts by construction (fixes r19's 5e7:
// 32-row fragments in row-major 128B rows are structurally 4-way).
// Achieved by computing per-chunk GLOBAL source addrs (gload's source is
// per-lane); LDS dest stays linear. Staging/cvt-gating/3-deep B/counted
// vmcnt = r8/r19 verbatim. C layout (r19-verified): col=lane&31,
// row=(r&3)+8*(r>>2)+4*(lane>>5).
__global__ __launch_bounds__(512, 2) void moe_gemm20(
    const u16* __restrict__ zr16, const u16* __restrict__ zi16,
    const u16* __restrict__ Wr16, const u16* __restrict__ Wi16,
    const float* __restrict__ gates, float* __restrict__ out)
{
    extern __shared__ u16 lds[];  // elems: A slots 0,16384; B: 32768 + s*16384

    // bm-local XCD remap: hw xcd = linear%8 owns bm in [xcd*4, xcd*4+4).
    const int linear = blockIdx.x + 32 * (blockIdx.y + 4 * blockIdx.z);
    const int xcd = linear & 7;
    const int bm = xcd * 4 + ((linear >> 3) & 3);
    const int grp2 = linear >> 5;   // 0..7
    const int bn = grp2 & 3;
    const int sel = grp2 >> 2;

    const int tid = threadIdx.x;
    const int lane = tid & 63;
    const int wid = tid >> 6;
    const int wr = wid >> 2;   // 0..1
    const int wc = wid & 3;    // 0..3

    // ---- staging addressing: fragment-order chunks ----
    // chunk c (0..2047): l=c&63, ks=(c>>6)&3, rb=c>>8;
    // global: row = rb*32 + (l&31), k = (l>>5)*8 + ks*16.
    int arow[4], gidx[4], brow[4];
#pragma unroll
    for (int j = 0; j < 4; ++j) {
        const int c = tid + j * 512;
        const int l = c & 63, ks = (c >> 6) & 3, rb = c >> 8;
        const int grA = bm * 256 + rb * 32 + (l & 31);
        const int grB = bn * 256 + rb * 32 + (l & 31);
        const int kk = (l >> 5) * 8 + ks * 16;
        arow[j] = grA * DIM + kk;
        gidx[j] = grA * NEXP;
        brow[j] = grB * DIM + kk;
    }

    // ---- fragment read addressing (elems): rb*2048 + ks*512 + lane*8 ----
    const int arbase = wr * 8192 + lane * 8;   // + m*2048 + ks*512
    const int brbase = wc * 4096 + lane * 8;   // + n*2048 + ks*512

    f32x16 acc[4][2];
#pragma unroll
    for (int m = 0; m < 4; ++m)
#pragma unroll
        for (int n = 0; n < 2; ++n)
#pragma unroll
            for (int e = 0; e < 16; ++e) acc[m][n][e] = 0.f;

    // ---- segment state: A tracks t+1, B tracks t+2 ----
    const u16* Asrc = sel ? zi16 : zr16;   // seg 0
    const u16* Bseg = Wr16;                // seg 0
    float sg[4];
#pragma unroll
    for (int j = 0; j < 4; ++j) sg[j] = gates[gidx[j]];

    // ---- prologue: A(0) cvt -> aslot0; B(0)->bslot0, B(1)->bslot1 ----
    {
        s16x8 ga[4];
#pragma unroll
        for (int j = 0; j < 4; ++j) ga[j] = *(const s16x8*)(Asrc + arow[j]);
#pragma unroll
        for (int i = 0; i < 4; ++i) GLOAD16(Bseg + brow[i], &lds[32768 + (i * 512 + tid) * 8]);
#pragma unroll
        for (int i = 0; i < 4; ++i) GLOAD16(Bseg + brow[i] + 64, &lds[32768 + 16384 + (i * 512 + tid) * 8]);
#pragma unroll
        for (int j = 0; j < 4; ++j) {
            s16x8 w;
#pragma unroll
            for (int q = 0; q < 8; ++q) w[q] = (short)f2bf(bf2f((u16)ga[j][q]) * sg[j]);
            *(s16x8*)&lds[(tid + j * 512) * 8] = w;
        }
        asm volatile("s_waitcnt vmcnt(4) lgkmcnt(0)" ::: "memory");
        __builtin_amdgcn_s_barrier();
    }

    int br = 0;  // B read slot = t%3
#pragma unroll 1
    for (int t = 0; t < NT; ++t) {
        const int tn1 = t + 1, tn2 = t + 2;
        if ((tn1 & 15) == 0) {  // A/gate state for t+1
            const int seg = tn1 >> 4;
            const int e = (seg >> 1) & 7;
            const int half = seg & 1;
            Asrc = (half ^ sel) ? zi16 : zr16;
            const float sgn = (sel == 0 && half == 1) ? -1.f : 1.f;
#pragma unroll
            for (int j = 0; j < 4; ++j) sg[j] = sgn * gates[gidx[j] + e];
        }
        if ((tn2 & 15) == 0) {  // B state for t+2
            const int seg = tn2 >> 4;
            const int e = (seg >> 1) & 7;
            Bseg = ((seg & 1) ? Wi16 : Wr16) + (size_t)e * DIM * DIM;
        }
        const int ka = (tn1 & 15) << 6;
        const int kb = (tn2 & 15) << 6;
        const int bs = (br == 0) ? 2 : br - 1;       // (t+2)%3
        const int ab = ((t & 1) << 14) + arbase;     // A read base
        const int bb = 32768 + br * 16384 + brbase;  // B read base
        const int sa = ((tn1 & 1) << 14);            // A staging dest
        const int sbB = 32768 + bs * 16384;          // B staging dest

        // ---- tile top: ga(t+1) reg loads FIRST, then B(t+2) gloads ----
        s16x8 ga[4];
#pragma unroll
        for (int j = 0; j < 4; ++j) ga[j] = *(const s16x8*)(Asrc + arow[j] + ka);
        GLOAD16(Bseg + brow[0] + kb, &lds[sbB + (0 * 512 + tid) * 8]);
        GLOAD16(Bseg + brow[1] + kb, &lds[sbB + (1 * 512 + tid) * 8]);
        GLOAD16(Bseg + brow[2] + kb, &lds[sbB + (2 * 512 + tid) * 8]);
        GLOAD16(Bseg + brow[3] + kb, &lds[sbB + (3 * 512 + tid) * 8]);

        // ==== ks0: reads + 8 MFMA ====
        s16x8 a0[4], b0[2];
#pragma unroll
        for (int n = 0; n < 2; ++n) b0[n] = *(const s16x8*)&lds[bb + n * 2048 + 0 * 512];
#pragma unroll
        for (int m = 0; m < 4; ++m) a0[m] = *(const s16x8*)&lds[ab + m * 2048 + 0 * 512];
        SGB();
        __builtin_amdgcn_s_setprio(1);
#pragma unroll
        for (int m = 0; m < 4; ++m)
#pragma unroll
            for (int n = 0; n < 2; ++n) acc[m][n] = MFMA32(a0[m], b0[n], acc[m][n]);
        __builtin_amdgcn_s_setprio(0);

        // ==== ks1: reads; MFMA + cvt j=0,1 inside window ====
        s16x8 a1[4], b1[2];
#pragma unroll
        for (int n = 0; n < 2; ++n) b1[n] = *(const s16x8*)&lds[bb + n * 2048 + 1 * 512];
#pragma unroll
        for (int m = 0; m < 4; ++m) a1[m] = *(const s16x8*)&lds[ab + m * 2048 + 1 * 512];
        SGB();
        __builtin_amdgcn_s_setprio(1);
#pragma unroll
        for (int m = 0; m < 4; ++m)
#pragma unroll
            for (int n = 0; n < 2; ++n) acc[m][n] = MFMA32(a1[m], b1[n], acc[m][n]);
#pragma unroll
        for (int j = 0; j < 2; ++j) {
            s16x8 w;
#pragma unroll
            for (int q = 0; q < 8; ++q) w[q] = (short)f2bf(bf2f((u16)ga[j][q]) * sg[j]);
            *(s16x8*)&lds[sa + (tid + j * 512) * 8] = w;
        }
        __builtin_amdgcn_s_setprio(0);

        // ==== ks2: reads; MFMA + cvt j=2,3 inside window ====
        s16x8 a2[4], b2[2];
#pragma unroll
        for (int n = 0; n < 2; ++n) b2[n] = *(const s16x8*)&lds[bb + n * 2048 + 2 * 512];
#pragma unroll
        for (int m = 0; m < 4; ++m) a2[m] = *(const s16x8*)&lds[ab + m * 2048 + 2 * 512];
        SGB();
        __builtin_amdgcn_s_setprio(1);
#pragma unroll
        for (int m = 0; m < 4; ++m)
#pragma unroll
            for (int n = 0; n < 2; ++n) acc[m][n] = MFMA32(a2[m], b2[n], acc[m][n]);
#pragma unroll
        for (int j = 2; j < 4; ++j) {
            s16x8 w;
#pragma unroll
            for (int q = 0; q < 8; ++q) w[q] = (short)f2bf(bf2f((u16)ga[j][q]) * sg[j]);
            *(s16x8*)&lds[sa + (tid + j * 512) * 8] = w;
        }
        __builtin_amdgcn_s_setprio(0);

        // ==== ks3: reads + 8 MFMA; counted drain; barrier ====
        s16x8 a3[4], b3[2];
#pragma unroll
        for (int n = 0; n < 2; ++n) b3[n] = *(const s16x8*)&lds[bb + n * 2048 + 3 * 512];
#pragma unroll
        for (int m = 0; m < 4; ++m) a3[m] = *(const s16x8*)&lds[ab + m * 2048 + 3 * 512];
        SGB();
        __builtin_amdgcn_s_setprio(1);
#pragma unroll
        for (int m = 0; m < 4; ++m)
#pragma unroll
            for (int n = 0; n < 2; ++n) acc[m][n] = MFMA32(a3[m], b3[n], acc[m][n]);
        __builtin_amdgcn_s_setprio(0);
        // B(t+1) complete (issued last tile); B(t+2)'s 4 stay in flight.
        asm volatile("s_waitcnt vmcnt(4) lgkmcnt(0)" ::: "memory");
        __builtin_amdgcn_s_barrier();

        br = (br == 2) ? 0 : br + 1;
    }
    asm volatile("s_waitcnt vmcnt(0)" ::: "memory");  // retire dead prefetches

    // ---- epilogue: 32x32 C layout: col=lane&31, row=(r&3)+8*(r>>2)+4*kg ----
    float* op = out + (size_t)sel * NTOK * DIM;
    const int kg = lane >> 5;
    const int col0 = bn * 256 + wc * 64 + (lane & 31);
    const int row0 = bm * 256 + wr * 128 + 4 * kg;
#pragma unroll
    for (int m = 0; m < 4; ++m)
#pragma unroll
        for (int n = 0; n < 2; ++n)
#pragma unroll
            for (int r = 0; r < 16; ++r) {
                const int row = row0 + m * 32 + (r & 3) + 8 * (r >> 2);
                op[(size_t)row * DIM + col0 + n * 32] = acc[m][n][r];
            }
}

extern "C" void kernel_launch(void* const* d_in, const int* in_sizes, int n_in,
                              void* d_out, int out_size, void* d_ws, size_t ws_size,
                              hipStream_t stream) {
    const float* zr = (const float*)d_in[0];
    const float* zi = (const float*)d_in[1];
    const float* Wg = (const float*)d_in[2];
    const float* bg = (const float*)d_in[3];
    const float* Wr = (const float*)d_in[4];
    const float* Wi = (const float*)d_in[5];
    float* out = (float*)d_out;

    u16* zr16 = (u16*)d_ws;
    u16* zi16 = zr16 + NELEMZ;
    u16* Wr16 = zi16 + NELEMZ;
    u16* Wi16 = Wr16 + NELEMZ;
    float* gates = (float*)(Wi16 + NELEMZ);

    cvt4_kernel<<<2048, 256, 0, stream>>>(zr, zi, Wr, Wi, zr16, zi16, Wr16, Wi16);
    gates_kernel<<<NTOK / 4, 256, 0, stream>>>(zr, zi, Wg, bg, gates);

    hipFuncSetAttribute((const void*)moe_gemm20,
                        hipFuncAttributeMaxDynamicSharedMemorySize, 163840);
    dim3 grid(NTOK / 256, DIM / 256, 2);
    moe_gemm20<<<grid, 512, 163840, stream>>>(zr16, zi16, Wr16, Wi16, gates, out);
}

// Round 21
// 535.061 us; speedup vs baseline: 1.4456x; 1.4456x over previous
//
#include <hip/hip_runtime.h>
#include <hip/hip_bf16.h>

#define NTOK 8192
#define DIM 1024
#define NEXP 8
#define NT 256   // virtual K tiles: 16 segments (expert x half) x 16 tiles of BK=64
#define BK 64
#define NELEMZ ((size_t)NTOK * DIM)

typedef float f32x4 __attribute__((ext_vector_type(4)));
typedef short s16x8 __attribute__((ext_vector_type(8)));
typedef unsigned short u16;
typedef unsigned short u16x4 __attribute__((ext_vector_type(4)));

__device__ __forceinline__ u16 f2bf(float f) {
    __hip_bfloat16 h = __float2bfloat16(f);
    return *reinterpret_cast<u16*>(&h);
}
__device__ __forceinline__ float bf2f(u16 u) {
    unsigned v = ((unsigned)u) << 16;
    return __uint_as_float(v);
}

#define GLOAD16(gsrc, ldst)                                                     \
    __builtin_amdgcn_global_load_lds(                                           \
        (const __attribute__((address_space(1))) void*)(gsrc),                  \
        (__attribute__((address_space(3))) void*)(ldst), 16, 0, 0)

#define MFMA16(a, b, c) __builtin_amdgcn_mfma_f32_16x16x32_bf16((a), (b), (c), 0, 0, 0)
#define SGB() __builtin_amdgcn_sched_barrier(0)

// ---------------- gates: softmax(z_flat @ Wg^T + bg) -> gates[n][e] ----------
__global__ __launch_bounds__(256) void gates_kernel(
    const float* __restrict__ zr, const float* __restrict__ zi,
    const float* __restrict__ Wg, const float* __restrict__ bg,
    float* __restrict__ gates)
{
    const int wave = threadIdx.x >> 6, lane = threadIdx.x & 63;
    const int n = blockIdx.x * 4 + wave;

    float v[32];
    const float* zrp = zr + (size_t)n * DIM;
    const float* zip = zi + (size_t)n * DIM;
#pragma unroll
    for (int j = 0; j < 16; ++j) v[j] = zrp[j * 64 + lane];
#pragma unroll
    for (int j = 0; j < 16; ++j) v[16 + j] = zip[j * 64 + lane];

    float s[NEXP];
#pragma unroll
    for (int e = 0; e < NEXP; ++e) {
        const float* wrow = Wg + (size_t)e * (2 * DIM);
        float a = 0.f;
#pragma unroll
        for (int j = 0; j < 32; ++j) a += v[j] * wrow[j * 64 + lane];
#pragma unroll
        for (int m = 32; m; m >>= 1) a += __shfl_xor(a, m);
        s[e] = a + bg[e];
    }
    float mx = s[0];
#pragma unroll
    for (int e = 1; e < NEXP; ++e) mx = fmaxf(mx, s[e]);
    float p[NEXP], sum = 0.f;
#pragma unroll
    for (int e = 0; e < NEXP; ++e) { p[e] = expf(s[e] - mx); sum += p[e]; }
    const float inv = 1.f / sum;
    if (lane == 0) {
#pragma unroll
        for (int e = 0; e < NEXP; ++e) gates[(size_t)n * NEXP + e] = p[e] * inv;
    }
}

// ---------------- fp32 -> bf16 conversion (z and W) ----------------
__global__ __launch_bounds__(256) void cvt4_kernel(
    const float* __restrict__ zr, const float* __restrict__ zi,
    const float* __restrict__ Wr, const float* __restrict__ Wi,
    u16* __restrict__ zr16, u16* __restrict__ zi16,
    u16* __restrict__ Wr16, u16* __restrict__ Wi16)
{
    const size_t total = NELEMZ / 4;
    for (size_t i = (size_t)blockIdx.x * 256 + threadIdx.x; i < total;
         i += (size_t)gridDim.x * 256) {
        f32x4 a = ((const f32x4*)zr)[i];
        f32x4 b = ((const f32x4*)zi)[i];
        f32x4 c = ((const f32x4*)Wr)[i];
        f32x4 d = ((const f32x4*)Wi)[i];
        u16x4 pa, pb, pc, pd;
#pragma unroll
        for (int j = 0; j < 4; ++j) {
            pa[j] = f2bf(a[j]); pb[j] = f2bf(b[j]);
            pc[j] = f2bf(c[j]); pd[j] = f2bf(d[j]);
        }
        ((u16x4*)zr16)[i] = pa;
        ((u16x4*)zi16)[i] = pb;
        ((u16x4*)Wr16)[i] = pc;
        ((u16x4*)Wi16)[i] = pd;
    }
}

// ---------------- main MoE GEMM: r8 pipelined 256x256 (session best) ---------
// 512 threads = 8 waves (2M x 4N), per-wave 128x64. Virtual K = 16 seg x 1024.
// LDS 160 KB: A dbuf 2x32KB (VALU cvt, gate*sign folded) + B tbuf 3x32KB
// (gload_lds for t+2). sched_barrier-pinned issue-ahead ds_reads; MFMA
// clusters in setprio windows; counted vmcnt(4) at tile end (B(t+2) stays in
// flight). Measured: 513-522 us GEMM, MfmaUtil ~50%, conflicts 0.
__global__ __launch_bounds__(512, 2) void moe_gemm8(
    const u16* __restrict__ zr16, const u16* __restrict__ zi16,
    const u16* __restrict__ Wr16, const u16* __restrict__ Wi16,
    const float* __restrict__ gates, float* __restrict__ out)
{
    extern __shared__ u16 lds[];
    const int linear = blockIdx.x + 32 * (blockIdx.y + 4 * blockIdx.z);
    const int xcd = linear & 7;
    const int bm = xcd * 4 + ((linear >> 3) & 3);
    const int grp2 = linear >> 5;
    const int bn = grp2 & 3;
    const int sel = grp2 >> 2;
    const int tid = threadIdx.x;
    const int lane = tid & 63;
    const int wid = tid >> 6;
    const int wr = wid >> 2, wc = wid & 3;
    const int srow = tid >> 3;
    const int schunk = (tid & 7) ^ (srow & 7);
    int arow[4], gidx[4], brow[4];
#pragma unroll
    for (int j = 0; j < 4; ++j) {
        const int gr = bm * 256 + srow + j * 64;
        arow[j] = gr * DIM + schunk * 8;
        gidx[j] = gr * NEXP;
        brow[j] = (bn * 256 + srow + j * 64) * DIM + schunk * 8;
    }
    const int cg = lane >> 4, l7 = lane & 7;
    const int ach0 = (cg ^ l7) * 8;
    const int ach1 = ((4 + cg) ^ l7) * 8;
    const int arbase = (wr * 128 + (lane & 15)) * BK;
    const int brbase = (wc * 64 + (lane & 15)) * BK;
    f32x4 acc[8][4];
#pragma unroll
    for (int m = 0; m < 8; ++m)
#pragma unroll
        for (int n = 0; n < 4; ++n) acc[m][n] = (f32x4){0.f, 0.f, 0.f, 0.f};
    const u16* Asrc = sel ? zi16 : zr16;
    const u16* Bseg = Wr16;
    float sg[4];
#pragma unroll
    for (int j = 0; j < 4; ++j) sg[j] = gates[gidx[j]];
    {
        s16x8 ga[4];
#pragma unroll
        for (int j = 0; j < 4; ++j) ga[j] = *(const s16x8*)(Asrc + arow[j]);
#pragma unroll
        for (int i = 0; i < 4; ++i) GLOAD16(Bseg + brow[i], &lds[32768 + (i * 512 + tid) * 8]);
#pragma unroll
        for (int i = 0; i < 4; ++i) GLOAD16(Bseg + brow[i] + 64, &lds[32768 + 16384 + (i * 512 + tid) * 8]);
#pragma unroll
        for (int j = 0; j < 4; ++j) {
            s16x8 w;
#pragma unroll
            for (int q = 0; q < 8; ++q) w[q] = (short)f2bf(bf2f((u16)ga[j][q]) * sg[j]);
            *(s16x8*)&lds[(tid + j * 512) * 8] = w;
        }
        asm volatile("s_waitcnt vmcnt(4) lgkmcnt(0)" ::: "memory");
        __builtin_amdgcn_s_barrier();
    }
    int br = 0;
#pragma unroll 1
    for (int t = 0; t < NT; ++t) {
        const int tn1 = t + 1, tn2 = t + 2;
        if ((tn1 & 15) == 0) {
            const int seg = tn1 >> 4;
            const int e = (seg >> 1) & 7;
            const int half = seg & 1;
            Asrc = (half ^ sel) ? zi16 : zr16;
            const float sgn = (sel == 0 && half == 1) ? -1.f : 1.f;
#pragma unroll
            for (int j = 0; j < 4; ++j) sg[j] = sgn * gates[gidx[j] + e];
        }
        if ((tn2 & 15) == 0) {
            const int seg = tn2 >> 4;
            const int e = (seg >> 1) & 7;
            Bseg = ((seg & 1) ? Wi16 : Wr16) + (size_t)e * DIM * DIM;
        }
        const int ka = (tn1 & 15) << 6;
        const int kb = (tn2 & 15) << 6;
        const int bs = (br == 0) ? 2 : br - 1;
        const int ab = ((t & 1) << 14) + arbase;
        const int bb = 32768 + br * 16384 + brbase;
        const int sa = ((tn1 & 1) << 14);
        const int sbB = 32768 + bs * 16384;
        s16x8 ga[4];
#pragma unroll
        for (int j = 0; j < 4; ++j) ga[j] = *(const s16x8*)(Asrc + arow[j] + ka);
        GLOAD16(Bseg + brow[0] + kb, &lds[sbB + (0 * 512 + tid) * 8]);
        GLOAD16(Bseg + brow[1] + kb, &lds[sbB + (1 * 512 + tid) * 8]);
        GLOAD16(Bseg + brow[2] + kb, &lds[sbB + (2 * 512 + tid) * 8]);
        GLOAD16(Bseg + brow[3] + kb, &lds[sbB + (3 * 512 + tid) * 8]);
        s16x8 b0[4], a0[4], a1[4], b1[4], a2[4], a3[4];
#pragma unroll
        for (int n = 0; n < 4; ++n) b0[n] = *(const s16x8*)&lds[bb + n * 1024 + ach0];
#pragma unroll
        for (int m = 0; m < 4; ++m) a0[m] = *(const s16x8*)&lds[ab + m * 1024 + ach0];
#pragma unroll
        for (int m = 0; m < 4; ++m) a1[m] = *(const s16x8*)&lds[ab + (m + 4) * 1024 + ach0];
        SGB();
        __builtin_amdgcn_s_setprio(1);
#pragma unroll
        for (int m = 0; m < 4; ++m)
#pragma unroll
            for (int n = 0; n < 4; ++n) acc[m][n] = MFMA16(a0[m], b0[n], acc[m][n]);
        __builtin_amdgcn_s_setprio(0);
#pragma unroll
        for (int n = 0; n < 4; ++n) b1[n] = *(const s16x8*)&lds[bb + n * 1024 + ach1];
#pragma unroll
        for (int m = 0; m < 4; ++m) a2[m] = *(const s16x8*)&lds[ab + m * 1024 + ach1];
        SGB();
        __builtin_amdgcn_s_setprio(1);
#pragma unroll
        for (int m = 0; m < 4; ++m)
#pragma unroll
            for (int n = 0; n < 4; ++n) acc[m + 4][n] = MFMA16(a1[m], b0[n], acc[m + 4][n]);
        __builtin_amdgcn_s_setprio(0);
#pragma unroll
        for (int j = 0; j < 2; ++j) {
            s16x8 w;
#pragma unroll
            for (int q = 0; q < 8; ++q) w[q] = (short)f2bf(bf2f((u16)ga[j][q]) * sg[j]);
            *(s16x8*)&lds[sa + (tid + j * 512) * 8] = w;
        }
#pragma unroll
        for (int m = 0; m < 4; ++m) a3[m] = *(const s16x8*)&lds[ab + (m + 4) * 1024 + ach1];
        SGB();
        __builtin_amdgcn_s_setprio(1);
#pragma unroll
        for (int m = 0; m < 4; ++m)
#pragma unroll
            for (int n = 0; n < 4; ++n) acc[m][n] = MFMA16(a2[m], b1[n], acc[m][n]);
        __builtin_amdgcn_s_setprio(0);
#pragma unroll
        for (int j = 2; j < 4; ++j) {
            s16x8 w;
#pragma unroll
            for (int q = 0; q < 8; ++q) w[q] = (short)f2bf(bf2f((u16)ga[j][q]) * sg[j]);
            *(s16x8*)&lds[sa + (tid + j * 512) * 8] = w;
        }
        __builtin_amdgcn_s_setprio(1);
#pragma unroll
        for (int m = 0; m < 4; ++m)
#pragma unroll
            for (int n = 0; n < 4; ++n) acc[m + 4][n] = MFMA16(a3[m], b1[n], acc[m + 4][n]);
        __builtin_amdgcn_s_setprio(0);
        asm volatile("s_waitcnt vmcnt(4) lgkmcnt(0)" ::: "memory");
        __builtin_amdgcn_s_barrier();
        br = (br == 2) ? 0 : br + 1;
    }
    asm volatile("s_waitcnt vmcnt(0)" ::: "memory");
    float* op = out + (size_t)sel * NTOK * DIM;
    const int col0 = bn * 256 + wc * 64 + (lane & 15);
    const int row0 = bm * 256 + wr * 128 + ((lane >> 4) << 2);
#pragma unroll
    for (int m = 0; m < 8; ++m)
#pragma unroll
        for (int n = 0; n < 4; ++n)
#pragma unroll
            for (int j = 0; j < 4; ++j)
                op[(size_t)(row0 + m * 16 + j) * DIM + col0 + n * 16] = acc[m][n][j];
}

extern "C" void kernel_launch(void* const* d_in, const int* in_sizes, int n_in,
                              void* d_out, int out_size, void* d_ws, size_t ws_size,
                              hipStream_t stream) {
    const float* zr = (const float*)d_in[0];
    const float* zi = (const float*)d_in[1];
    const float* Wg = (const float*)d_in[2];
    const float* bg = (const float*)d_in[3];
    const float* Wr = (const float*)d_in[4];
    const float* Wi = (const float*)d_in[5];
    float* out = (float*)d_out;

    u16* zr16 = (u16*)d_ws;
    u16* zi16 = zr16 + NELEMZ;
    u16* Wr16 = zi16 + NELEMZ;
    u16* Wi16 = Wr16 + NELEMZ;
    float* gates = (float*)(Wi16 + NELEMZ);

    cvt4_kernel<<<2048, 256, 0, stream>>>(zr, zi, Wr, Wi, zr16, zi16, Wr16, Wi16);
    gates_kernel<<<NTOK / 4, 256, 0, stream>>>(zr, zi, Wg, bg, gates);

    hipFuncSetAttribute((const void*)moe_gemm8,
                        hipFuncAttributeMaxDynamicSharedMemorySize, 163840);
    dim3 grid(NTOK / 256, DIM / 256, 2);
    moe_gemm8<<<grid, 512, 163840, stream>>>(zr16, zi16, Wr16, Wi16, gates, out);
}